// Round 10
// baseline (922.224 us; speedup 1.0000x reference)
//
#include <hip/hip_runtime.h>

// HGNN+ conv: y = dv*(H * de*(H^T * (dv*(XW+b)))) + (XW+b)
// Pipeline (all on `stream`) — ZERO global atomics:
//   1. GEMM: d_out = X*W + b                     (x_mapped)
//   2. kA: per-block LDS histograms -> partials   (edge: 20K bins/80KB static LDS;
//                                                  node: 4 ranges x 25K bins/100KB static LDS)
//   3. kB: partials -> per-(block,bin) excl offsets + per-bin counts (coalesced)
//   4. scan -> CSR starts
//   5. kC: placement via LDS cursors (start+partial), scattered int2 slot stores
//        edge side: eslot[s] = {node, hv*dv[node]} ; node side: nslot[s] = {edge, hv}
//   6. wave-per-edge gather: E2[e] = de[e] * sum val*xm[idx]
//   7. wave-per-node gather: y[n] = dv[n] * sum val*E2[idx] + xm[n]
// Rationale (r7 counters): k_hist 132us @ WRITE_SIZE 99MB == 3.2M atomics x 32B
// write-through; cursor scatter had the same floor. Global-atomic throughput
// (~24/ns) was the bottleneck -> block-local stable counting sort instead.

#define F 128
#define NB 64          // sort blocks (chunk = NNZ/NB = 25000)
#define M_E 20000      // edge bins (80KB LDS)
#define RB_N 25000     // node bins per range (100KB LDS)
#define R_N 4          // node ranges (4 x 25000 = 100000)

// ---- Pass A: per-block LDS histogram -> partials -------------------------
__global__ __launch_bounds__(256) void kA_e(const int* __restrict__ ei,
                                            int* __restrict__ part2, int nnz) {
    __shared__ int sh[M_E];
    int b = blockIdx.x, t = threadIdx.x;
    for (int k = t; k < M_E; k += 256) sh[k] = 0;
    __syncthreads();
    int ch = (nnz + NB - 1) / NB;
    int i0 = b * ch, i1 = i0 + ch < nnz ? i0 + ch : nnz;
    for (int i = i0 + t; i < i1; i += 256) atomicAdd(&sh[ei[i]], 1);
    __syncthreads();
    for (int k = t; k < M_E; k += 256) part2[(size_t)b * M_E + k] = sh[k];
}

__global__ __launch_bounds__(256) void kA_n(const int* __restrict__ ni,
                                            int* __restrict__ partN2, int nnz) {
    __shared__ int sh[RB_N];
    int b = blockIdx.x, t = threadIdx.x;
    int ch = (nnz + NB - 1) / NB;
    int i0 = b * ch, i1 = i0 + ch < nnz ? i0 + ch : nnz;
    for (int r = 0; r < R_N; ++r) {
        for (int k = t; k < RB_N; k += 256) sh[k] = 0;
        __syncthreads();
        int lo = r * RB_N;
        for (int i = i0 + t; i < i1; i += 256) {
            int lb = ni[i] - lo;
            if ((unsigned)lb < (unsigned)RB_N) atomicAdd(&sh[lb], 1);
        }
        __syncthreads();
        for (int k = t; k < RB_N; k += 256)
            partN2[((size_t)(r * NB + b)) * RB_N + k] = sh[k];
        __syncthreads();
    }
}

// ---- Pass B: within-bin exclusive prefix over blocks + totals ------------
__global__ void kB(int* __restrict__ part2, int* __restrict__ cnt, int bins) {
    int bin = blockIdx.x * blockDim.x + threadIdx.x;
    if (bin >= bins) return;
    int run = 0;
    for (int b = 0; b < NB; ++b) {
        size_t idx = (size_t)b * bins + bin;
        int v = part2[idx];
        part2[idx] = run;
        run += v;
    }
    cnt[bin] = run;
}

// ---- hierarchical exclusive scan (cnt -> start) --------------------------
__global__ void k_scan1(const int* __restrict__ cnt, int* __restrict__ excl,
                        int* __restrict__ part, int n) {
    __shared__ int s[256];
    int t = threadIdx.x;
    int base = blockIdx.x * 1024 + t * 4;
    int v0 = (base + 0 < n) ? cnt[base + 0] : 0;
    int v1 = (base + 1 < n) ? cnt[base + 1] : 0;
    int v2 = (base + 2 < n) ? cnt[base + 2] : 0;
    int v3 = (base + 3 < n) ? cnt[base + 3] : 0;
    s[t] = v0 + v1 + v2 + v3;
    __syncthreads();
    for (int off = 1; off < 256; off <<= 1) {
        int add = (t >= off) ? s[t - off] : 0;
        __syncthreads();
        s[t] += add;
        __syncthreads();
    }
    int r = (t > 0) ? s[t - 1] : 0;
    if (base + 0 < n) excl[base + 0] = r; r += v0;
    if (base + 1 < n) excl[base + 1] = r; r += v1;
    if (base + 2 < n) excl[base + 2] = r; r += v2;
    if (base + 3 < n) excl[base + 3] = r;
    if (t == 255) part[blockIdx.x] = s[255];
}

__global__ void k_scan2(int* __restrict__ part, int n) {
    __shared__ int s[256];
    int t = threadIdx.x;
    s[t] = (t < n) ? part[t] : 0;
    __syncthreads();
    for (int off = 1; off < 256; off <<= 1) {
        int add = (t >= off) ? s[t - off] : 0;
        __syncthreads();
        s[t] += add;
        __syncthreads();
    }
    if (t < n) part[t] = (t > 0) ? s[t - 1] : 0;
}

__global__ void k_scan3(int* __restrict__ start, const int* __restrict__ part, int n) {
    int i = blockIdx.x * blockDim.x + threadIdx.x;
    if (i < n) start[i] += part[i >> 10];
}

// ---- Pass C: placement via LDS cursors (no global atomics) ---------------
__global__ __launch_bounds__(256) void kC_e(const int* __restrict__ ei, const int* __restrict__ ni,
                                            const float* __restrict__ hv, const float* __restrict__ dv,
                                            const int* __restrict__ start, const int* __restrict__ part2,
                                            int2* __restrict__ eslot, int nnz) {
    __shared__ int sh[M_E];
    int b = blockIdx.x, t = threadIdx.x;
    for (int k = t; k < M_E; k += 256)
        sh[k] = start[k] + part2[(size_t)b * M_E + k];
    __syncthreads();
    int ch = (nnz + NB - 1) / NB;
    int i0 = b * ch, i1 = i0 + ch < nnz ? i0 + ch : nnz;
    for (int i = i0 + t; i < i1; i += 256) {
        int e = ei[i], nd = ni[i];
        float v = hv[i] * dv[nd];
        int p = atomicAdd(&sh[e], 1);
        eslot[p] = make_int2(nd, __float_as_int(v));
    }
}

__global__ __launch_bounds__(256) void kC_n(const int* __restrict__ ei, const int* __restrict__ ni,
                                            const float* __restrict__ hv,
                                            const int* __restrict__ start, const int* __restrict__ partN2,
                                            int2* __restrict__ nslot, int nnz) {
    __shared__ int sh[RB_N];
    int b = blockIdx.x, t = threadIdx.x;
    int ch = (nnz + NB - 1) / NB;
    int i0 = b * ch, i1 = i0 + ch < nnz ? i0 + ch : nnz;
    for (int r = 0; r < R_N; ++r) {
        int lo = r * RB_N;
        for (int k = t; k < RB_N; k += 256)
            sh[k] = start[lo + k] + partN2[((size_t)(r * NB + b)) * RB_N + k];
        __syncthreads();
        for (int i = i0 + t; i < i1; i += 256) {
            int lb = ni[i] - lo;
            if ((unsigned)lb < (unsigned)RB_N) {
                int e = ei[i];
                float h = hv[i];
                int p = atomicAdd(&sh[lb], 1);
                nslot[p] = make_int2(e, __float_as_int(h));
            }
        }
        __syncthreads();
    }
}

__device__ __forceinline__ float f4_get(const float4& v, int k) {
    return k == 0 ? v.x : k == 1 ? v.y : k == 2 ? v.z : v.w;
}

// ---- GEMM: y[N,128] = x[N,128] @ w[128,128] + bias -----------------------
__global__ __launch_bounds__(256) void k_gemm(const float* __restrict__ x,
                                              const float* __restrict__ w,
                                              const float* __restrict__ bias,
                                              float* __restrict__ y, int N) {
    __shared__ float sw[32 * 128];
    __shared__ float sx[128 * 36];
    int t = threadIdx.x;
    int row0 = blockIdx.x * 128;
    int cg = (t & 15) * 8;
    int rg = (t >> 4) * 8;
    float acc[8][8];
#pragma unroll
    for (int a = 0; a < 8; a++)
#pragma unroll
        for (int b = 0; b < 8; b++) acc[a][b] = 0.f;

    const float4* x4 = (const float4*)x;
    const float4* w4 = (const float4*)w;

    for (int kc = 0; kc < 4; ++kc) {
        __syncthreads();
        for (int i = t; i < 1024; i += 256) {
            int k = i >> 5, c4 = i & 31;
            ((float4*)sw)[i] = w4[(kc * 32 + k) * 32 + c4];
        }
        for (int i = t; i < 1024; i += 256) {
            int r = i >> 3, c4 = i & 7;
            float4 vv = make_float4(0.f, 0.f, 0.f, 0.f);
            if (row0 + r < N) vv = x4[(size_t)(row0 + r) * 32 + kc * 8 + c4];
            *(float4*)&sx[r * 36 + c4 * 4] = vv;
        }
        __syncthreads();
#pragma unroll
        for (int k4 = 0; k4 < 8; ++k4) {
            float4 xa[8];
#pragma unroll
            for (int rr = 0; rr < 8; rr++)
                xa[rr] = *(const float4*)&sx[(rg + rr) * 36 + k4 * 4];
#pragma unroll
            for (int kk = 0; kk < 4; kk++) {
                float4 wa0 = *(const float4*)&sw[(k4 * 4 + kk) * 128 + cg];
                float4 wa1 = *(const float4*)&sw[(k4 * 4 + kk) * 128 + cg + 4];
#pragma unroll
                for (int rr = 0; rr < 8; rr++) {
                    float xv = f4_get(xa[rr], kk);
                    acc[rr][0] += xv * wa0.x; acc[rr][1] += xv * wa0.y;
                    acc[rr][2] += xv * wa0.z; acc[rr][3] += xv * wa0.w;
                    acc[rr][4] += xv * wa1.x; acc[rr][5] += xv * wa1.y;
                    acc[rr][6] += xv * wa1.z; acc[rr][7] += xv * wa1.w;
                }
            }
        }
    }

    float4 b0 = *(const float4*)&bias[cg];
    float4 b1 = *(const float4*)&bias[cg + 4];
#pragma unroll
    for (int rr = 0; rr < 8; rr++) {
        int r = row0 + rg + rr;
        if (r < N) {
            float4 o0 = make_float4(acc[rr][0] + b0.x, acc[rr][1] + b0.y,
                                    acc[rr][2] + b0.z, acc[rr][3] + b0.w);
            float4 o1 = make_float4(acc[rr][4] + b1.x, acc[rr][5] + b1.y,
                                    acc[rr][6] + b1.z, acc[rr][7] + b1.w);
            *(float4*)&y[(size_t)r * F + cg]     = o0;
            *(float4*)&y[(size_t)r * F + cg + 4] = o1;
        }
    }
}

// ---- gathers -------------------------------------------------------------
__global__ __launch_bounds__(256) void k_edge(const float* __restrict__ xm,
                                              const int2* __restrict__ slot,
                                              const float* __restrict__ de,
                                              const int* __restrict__ start,
                                              const int* __restrict__ cnt,
                                              float* __restrict__ E2, int M) {
    int wid = blockIdx.x * 4 + (threadIdx.x >> 6);
    if (wid >= M) return;
    int lane = threadIdx.x & 63;
    int hl = lane >> 5;
    int l  = lane & 31;
    int p = start[wid], c = cnt[wid];
    float a0 = 0.f, a1 = 0.f, a2 = 0.f, a3 = 0.f;
    int j = hl;
    for (; j + 2 < c; j += 4) {
        int2 s0 = slot[p + j];
        int2 s1 = slot[p + j + 2];
        float c0 = __int_as_float(s0.y), c1 = __int_as_float(s1.y);
        float4 v0 = *(const float4*)(xm + (size_t)s0.x * F + l * 4);
        float4 v1 = *(const float4*)(xm + (size_t)s1.x * F + l * 4);
        a0 += c0 * v0.x + c1 * v1.x;
        a1 += c0 * v0.y + c1 * v1.y;
        a2 += c0 * v0.z + c1 * v1.z;
        a3 += c0 * v0.w + c1 * v1.w;
    }
    if (j < c) {
        int2 s0 = slot[p + j];
        float c0 = __int_as_float(s0.y);
        float4 v0 = *(const float4*)(xm + (size_t)s0.x * F + l * 4);
        a0 += c0 * v0.x; a1 += c0 * v0.y; a2 += c0 * v0.z; a3 += c0 * v0.w;
    }
    a0 += __shfl_xor(a0, 32);
    a1 += __shfl_xor(a1, 32);
    a2 += __shfl_xor(a2, 32);
    a3 += __shfl_xor(a3, 32);
    if (hl == 0) {
        float s = de[wid];
        *(float4*)(E2 + (size_t)wid * F + l * 4) =
            make_float4(a0 * s, a1 * s, a2 * s, a3 * s);
    }
}

__global__ __launch_bounds__(256) void k_node(const float* xm,
                                              const int2* __restrict__ slot,
                                              const float* __restrict__ dv,
                                              const int* __restrict__ start,
                                              const int* __restrict__ cnt,
                                              const float* __restrict__ E2,
                                              float* out, int N) {
    int wid = blockIdx.x * 4 + (threadIdx.x >> 6);
    if (wid >= N) return;
    int lane = threadIdx.x & 63;
    int hl = lane >> 5;
    int l  = lane & 31;
    int p = start[wid], c = cnt[wid];
    float a0 = 0.f, a1 = 0.f, a2 = 0.f, a3 = 0.f;
    int j = hl;
    for (; j + 2 < c; j += 4) {
        int2 s0 = slot[p + j];
        int2 s1 = slot[p + j + 2];
        float c0 = __int_as_float(s0.y), c1 = __int_as_float(s1.y);
        float4 v0 = *(const float4*)(E2 + (size_t)s0.x * F + l * 4);
        float4 v1 = *(const float4*)(E2 + (size_t)s1.x * F + l * 4);
        a0 += c0 * v0.x + c1 * v1.x;
        a1 += c0 * v0.y + c1 * v1.y;
        a2 += c0 * v0.z + c1 * v1.z;
        a3 += c0 * v0.w + c1 * v1.w;
    }
    if (j < c) {
        int2 s0 = slot[p + j];
        float c0 = __int_as_float(s0.y);
        float4 v0 = *(const float4*)(E2 + (size_t)s0.x * F + l * 4);
        a0 += c0 * v0.x; a1 += c0 * v0.y; a2 += c0 * v0.z; a3 += c0 * v0.w;
    }
    a0 += __shfl_xor(a0, 32);
    a1 += __shfl_xor(a1, 32);
    a2 += __shfl_xor(a2, 32);
    a3 += __shfl_xor(a3, 32);
    if (hl == 0) {
        float dvn = dv[wid];
        float4 xv = *(const float4*)(xm + (size_t)wid * F + l * 4);
        *(float4*)(out + (size_t)wid * F + l * 4) =
            make_float4(a0 * dvn + xv.x, a1 * dvn + xv.y,
                        a2 * dvn + xv.z, a3 * dvn + xv.w);
    }
}

extern "C" void kernel_launch(void* const* d_in, const int* in_sizes, int n_in,
                              void* d_out, int out_size, void* d_ws, size_t ws_size,
                              hipStream_t stream) {
    const float* x      = (const float*)d_in[0];
    const float* w      = (const float*)d_in[1];
    const float* bias   = (const float*)d_in[2];
    const int*   ni     = (const int*)d_in[3];
    const int*   ei     = (const int*)d_in[4];
    const float* hv     = (const float*)d_in[5];
    const float* dv     = (const float*)d_in[6];
    const float* de     = (const float*)d_in[7];
    float* out = (float*)d_out;

    const int N   = in_sizes[0] / F;   // 100000
    const int NNZ = in_sizes[3];       // 1600000
    const int M   = in_sizes[7];       // 20000 (== M_E)

    // workspace layout (4B units) — ~57.3 MB total
    int* wsp        = (int*)d_ws;
    int* edge_cnt   = wsp;                        // 20000
    int* node_cnt   = edge_cnt + M;               // 100000
    int* edge_start = node_cnt + N;               // 20000
    int* node_start = edge_start + M;             // 100000
    int* partE      = node_start + N;             // 256
    int* partN      = partE + 256;                // 256
    int* partE2     = partN + 256;                // NB*20000    = 1.28M
    int* partN2     = partE2 + (size_t)NB * M_E;  // R_N*NB*25000= 6.4M
    int2* eslot     = (int2*)(partN2 + (size_t)R_N * NB * RB_N); // NNZ int2
    int2* nslot     = eslot + NNZ;                // NNZ int2
    // E2 aliases partN2 (consumed by kC_n before k_edge writes E2)
    float* E2       = (float*)partN2;             // M*F floats (10.24MB <= 25.6MB)

    const int gScanE = (M + 1023) / 1024;    // 20
    const int gScanN = (N + 1023) / 1024;    // 98

    k_gemm<<<(N + 127) / 128, 256, 0, stream>>>(x, w, bias, out, N);

    kA_e<<<NB, 256, 0, stream>>>(ei, partE2, NNZ);
    kA_n<<<NB, 256, 0, stream>>>(ni, partN2, NNZ);

    kB<<<(M + 255) / 256, 256, 0, stream>>>(partE2, edge_cnt, M);
    for (int r = 0; r < R_N; ++r)
        kB<<<(RB_N + 255) / 256, 256, 0, stream>>>(partN2 + (size_t)r * NB * RB_N,
                                                   node_cnt + (size_t)r * RB_N, RB_N);

    k_scan1<<<gScanE, 256, 0, stream>>>(edge_cnt, edge_start, partE, M);
    k_scan1<<<gScanN, 256, 0, stream>>>(node_cnt, node_start, partN, N);
    k_scan2<<<1, 256, 0, stream>>>(partE, gScanE);
    k_scan2<<<1, 256, 0, stream>>>(partN, gScanN);
    k_scan3<<<(M + 255) / 256, 256, 0, stream>>>(edge_start, partE, M);
    k_scan3<<<(N + 255) / 256, 256, 0, stream>>>(node_start, partN, N);

    kC_e<<<NB, 256, 0, stream>>>(ei, ni, hv, dv, edge_start, partE2, eslot, NNZ);
    kC_n<<<NB, 256, 0, stream>>>(ei, ni, hv, node_start, partN2, nslot, NNZ);

    k_edge<<<(M + 3) / 4, 256, 0, stream>>>(out, eslot, de, edge_start, edge_cnt, E2, M);
    k_node<<<(N + 3) / 4, 256, 0, stream>>>(out, nslot, dv, node_start, node_cnt, E2, out, N);
}

// Round 11
// 588.865 us; speedup vs baseline: 1.5661x; 1.5661x over previous
//
#include <hip/hip_runtime.h>

// HGNN+ conv: y = dv*(H * de*(H^T * (dv*(XW+b)))) + (XW+b)
// ZERO global atomics. r10 lesson: LDS counting sort was right (atomic
// write-through gone) but grid NB=64 starved the chip (kC_n occupancy 2.77%).
// Fix: (chunk,range) 2D grid for node side (64x4=256 blocks), 256 chunks for
// edge side, 512 threads/block on all big-LDS sort kernels.

#define F 128
#define NBE 256        // edge-side chunks (chunk = 6250)
#define NBN 64         // node-side chunks (chunk = 25000)
#define M_E 20000      // edge bins (80KB LDS)
#define RB_N 25000     // node bins per range (100KB LDS)
#define R_N 4          // node ranges

// ---- Pass A: per-block LDS histogram -> partials -------------------------
__global__ __launch_bounds__(512) void kA_e(const int* __restrict__ ei,
                                            int* __restrict__ part2, int nnz) {
    __shared__ int sh[M_E];
    int b = blockIdx.x, t = threadIdx.x;
    for (int k = t; k < M_E; k += 512) sh[k] = 0;
    __syncthreads();
    int ch = (nnz + NBE - 1) / NBE;
    int i0 = b * ch, i1 = i0 + ch < nnz ? i0 + ch : nnz;
    for (int i = i0 + t; i < i1; i += 512) atomicAdd(&sh[ei[i]], 1);
    __syncthreads();
    for (int k = t; k < M_E; k += 512) part2[(size_t)b * M_E + k] = sh[k];
}

// block (b,r): b = blockIdx.x>>2 (chunk), r = blockIdx.x&3 (range)
__global__ __launch_bounds__(512) void kA_n(const int* __restrict__ ni,
                                            int* __restrict__ partN2, int nnz) {
    __shared__ int sh[RB_N];
    int b = blockIdx.x >> 2, r = blockIdx.x & 3, t = threadIdx.x;
    for (int k = t; k < RB_N; k += 512) sh[k] = 0;
    __syncthreads();
    int ch = (nnz + NBN - 1) / NBN;
    int i0 = b * ch, i1 = i0 + ch < nnz ? i0 + ch : nnz;
    int lo = r * RB_N;
    for (int i = i0 + t; i < i1; i += 512) {
        int lb = ni[i] - lo;
        if ((unsigned)lb < (unsigned)RB_N) atomicAdd(&sh[lb], 1);
    }
    __syncthreads();
    for (int k = t; k < RB_N; k += 512)
        partN2[((size_t)(r * NBN + b)) * RB_N + k] = sh[k];
}

// ---- Pass B: within-bin exclusive prefix over blocks + totals ------------
__global__ void kB(int* __restrict__ part2, int* __restrict__ cnt, int bins, int nb) {
    int bin = blockIdx.x * blockDim.x + threadIdx.x;
    if (bin >= bins) return;
    int run = 0;
#pragma unroll 8
    for (int b = 0; b < nb; ++b) {
        size_t idx = (size_t)b * bins + bin;
        int v = part2[idx];
        part2[idx] = run;
        run += v;
    }
    cnt[bin] = run;
}

// ---- hierarchical exclusive scan (cnt -> start) --------------------------
__global__ void k_scan1(const int* __restrict__ cnt, int* __restrict__ excl,
                        int* __restrict__ part, int n) {
    __shared__ int s[256];
    int t = threadIdx.x;
    int base = blockIdx.x * 1024 + t * 4;
    int v0 = (base + 0 < n) ? cnt[base + 0] : 0;
    int v1 = (base + 1 < n) ? cnt[base + 1] : 0;
    int v2 = (base + 2 < n) ? cnt[base + 2] : 0;
    int v3 = (base + 3 < n) ? cnt[base + 3] : 0;
    s[t] = v0 + v1 + v2 + v3;
    __syncthreads();
    for (int off = 1; off < 256; off <<= 1) {
        int add = (t >= off) ? s[t - off] : 0;
        __syncthreads();
        s[t] += add;
        __syncthreads();
    }
    int r = (t > 0) ? s[t - 1] : 0;
    if (base + 0 < n) excl[base + 0] = r; r += v0;
    if (base + 1 < n) excl[base + 1] = r; r += v1;
    if (base + 2 < n) excl[base + 2] = r; r += v2;
    if (base + 3 < n) excl[base + 3] = r;
    if (t == 255) part[blockIdx.x] = s[255];
}

__global__ void k_scan2(int* __restrict__ part, int n) {
    __shared__ int s[256];
    int t = threadIdx.x;
    s[t] = (t < n) ? part[t] : 0;
    __syncthreads();
    for (int off = 1; off < 256; off <<= 1) {
        int add = (t >= off) ? s[t - off] : 0;
        __syncthreads();
        s[t] += add;
        __syncthreads();
    }
    if (t < n) part[t] = (t > 0) ? s[t - 1] : 0;
}

__global__ void k_scan3(int* __restrict__ start, const int* __restrict__ part, int n) {
    int i = blockIdx.x * blockDim.x + threadIdx.x;
    if (i < n) start[i] += part[i >> 10];
}

// ---- Pass C: placement via LDS cursors (no global atomics) ---------------
__global__ __launch_bounds__(512) void kC_e(const int* __restrict__ ei, const int* __restrict__ ni,
                                            const float* __restrict__ hv, const float* __restrict__ dv,
                                            const int* __restrict__ start, const int* __restrict__ part2,
                                            int2* __restrict__ eslot, int nnz) {
    __shared__ int sh[M_E];
    int b = blockIdx.x, t = threadIdx.x;
    for (int k = t; k < M_E; k += 512)
        sh[k] = start[k] + part2[(size_t)b * M_E + k];
    __syncthreads();
    int ch = (nnz + NBE - 1) / NBE;
    int i0 = b * ch, i1 = i0 + ch < nnz ? i0 + ch : nnz;
    for (int i = i0 + t; i < i1; i += 512) {
        int e = ei[i], nd = ni[i];
        float v = hv[i] * dv[nd];
        int p = atomicAdd(&sh[e], 1);
        eslot[p] = make_int2(nd, __float_as_int(v));
    }
}

__global__ __launch_bounds__(512) void kC_n(const int* __restrict__ ei, const int* __restrict__ ni,
                                            const float* __restrict__ hv,
                                            const int* __restrict__ start, const int* __restrict__ partN2,
                                            int2* __restrict__ nslot, int nnz) {
    __shared__ int sh[RB_N];
    int b = blockIdx.x >> 2, r = blockIdx.x & 3, t = threadIdx.x;
    int lo = r * RB_N;
    for (int k = t; k < RB_N; k += 512)
        sh[k] = start[lo + k] + partN2[((size_t)(r * NBN + b)) * RB_N + k];
    __syncthreads();
    int ch = (nnz + NBN - 1) / NBN;
    int i0 = b * ch, i1 = i0 + ch < nnz ? i0 + ch : nnz;
    for (int i = i0 + t; i < i1; i += 512) {
        int lb = ni[i] - lo;
        if ((unsigned)lb < (unsigned)RB_N) {
            int e = ei[i];
            float h = hv[i];
            int p = atomicAdd(&sh[lb], 1);
            nslot[p] = make_int2(e, __float_as_int(h));
        }
    }
}

__device__ __forceinline__ float f4_get(const float4& v, int k) {
    return k == 0 ? v.x : k == 1 ? v.y : k == 2 ? v.z : v.w;
}

// ---- GEMM: y[N,128] = x[N,128] @ w[128,128] + bias -----------------------
__global__ __launch_bounds__(256) void k_gemm(const float* __restrict__ x,
                                              const float* __restrict__ w,
                                              const float* __restrict__ bias,
                                              float* __restrict__ y, int N) {
    __shared__ float sw[32 * 128];
    __shared__ float sx[128 * 36];
    int t = threadIdx.x;
    int row0 = blockIdx.x * 128;
    int cg = (t & 15) * 8;
    int rg = (t >> 4) * 8;
    float acc[8][8];
#pragma unroll
    for (int a = 0; a < 8; a++)
#pragma unroll
        for (int b = 0; b < 8; b++) acc[a][b] = 0.f;

    const float4* x4 = (const float4*)x;
    const float4* w4 = (const float4*)w;

    for (int kc = 0; kc < 4; ++kc) {
        __syncthreads();
        for (int i = t; i < 1024; i += 256) {
            int k = i >> 5, c4 = i & 31;
            ((float4*)sw)[i] = w4[(kc * 32 + k) * 32 + c4];
        }
        for (int i = t; i < 1024; i += 256) {
            int r = i >> 3, c4 = i & 7;
            float4 vv = make_float4(0.f, 0.f, 0.f, 0.f);
            if (row0 + r < N) vv = x4[(size_t)(row0 + r) * 32 + kc * 8 + c4];
            *(float4*)&sx[r * 36 + c4 * 4] = vv;
        }
        __syncthreads();
#pragma unroll
        for (int k4 = 0; k4 < 8; ++k4) {
            float4 xa[8];
#pragma unroll
            for (int rr = 0; rr < 8; rr++)
                xa[rr] = *(const float4*)&sx[(rg + rr) * 36 + k4 * 4];
#pragma unroll
            for (int kk = 0; kk < 4; kk++) {
                float4 wa0 = *(const float4*)&sw[(k4 * 4 + kk) * 128 + cg];
                float4 wa1 = *(const float4*)&sw[(k4 * 4 + kk) * 128 + cg + 4];
#pragma unroll
                for (int rr = 0; rr < 8; rr++) {
                    float xv = f4_get(xa[rr], kk);
                    acc[rr][0] += xv * wa0.x; acc[rr][1] += xv * wa0.y;
                    acc[rr][2] += xv * wa0.z; acc[rr][3] += xv * wa0.w;
                    acc[rr][4] += xv * wa1.x; acc[rr][5] += xv * wa1.y;
                    acc[rr][6] += xv * wa1.z; acc[rr][7] += xv * wa1.w;
                }
            }
        }
    }

    float4 b0 = *(const float4*)&bias[cg];
    float4 b1 = *(const float4*)&bias[cg + 4];
#pragma unroll
    for (int rr = 0; rr < 8; rr++) {
        int r = row0 + rg + rr;
        if (r < N) {
            float4 o0 = make_float4(acc[rr][0] + b0.x, acc[rr][1] + b0.y,
                                    acc[rr][2] + b0.z, acc[rr][3] + b0.w);
            float4 o1 = make_float4(acc[rr][4] + b1.x, acc[rr][5] + b1.y,
                                    acc[rr][6] + b1.z, acc[rr][7] + b1.w);
            *(float4*)&y[(size_t)r * F + cg]     = o0;
            *(float4*)&y[(size_t)r * F + cg + 4] = o1;
        }
    }
}

// ---- gathers -------------------------------------------------------------
__global__ __launch_bounds__(256) void k_edge(const float* __restrict__ xm,
                                              const int2* __restrict__ slot,
                                              const float* __restrict__ de,
                                              const int* __restrict__ start,
                                              const int* __restrict__ cnt,
                                              float* __restrict__ E2, int M) {
    int wid = blockIdx.x * 4 + (threadIdx.x >> 6);
    if (wid >= M) return;
    int lane = threadIdx.x & 63;
    int hl = lane >> 5;
    int l  = lane & 31;
    int p = start[wid], c = cnt[wid];
    float a0 = 0.f, a1 = 0.f, a2 = 0.f, a3 = 0.f;
    int j = hl;
    for (; j + 2 < c; j += 4) {
        int2 s0 = slot[p + j];
        int2 s1 = slot[p + j + 2];
        float c0 = __int_as_float(s0.y), c1 = __int_as_float(s1.y);
        float4 v0 = *(const float4*)(xm + (size_t)s0.x * F + l * 4);
        float4 v1 = *(const float4*)(xm + (size_t)s1.x * F + l * 4);
        a0 += c0 * v0.x + c1 * v1.x;
        a1 += c0 * v0.y + c1 * v1.y;
        a2 += c0 * v0.z + c1 * v1.z;
        a3 += c0 * v0.w + c1 * v1.w;
    }
    if (j < c) {
        int2 s0 = slot[p + j];
        float c0 = __int_as_float(s0.y);
        float4 v0 = *(const float4*)(xm + (size_t)s0.x * F + l * 4);
        a0 += c0 * v0.x; a1 += c0 * v0.y; a2 += c0 * v0.z; a3 += c0 * v0.w;
    }
    a0 += __shfl_xor(a0, 32);
    a1 += __shfl_xor(a1, 32);
    a2 += __shfl_xor(a2, 32);
    a3 += __shfl_xor(a3, 32);
    if (hl == 0) {
        float s = de[wid];
        *(float4*)(E2 + (size_t)wid * F + l * 4) =
            make_float4(a0 * s, a1 * s, a2 * s, a3 * s);
    }
}

__global__ __launch_bounds__(256) void k_node(const float* xm,
                                              const int2* __restrict__ slot,
                                              const float* __restrict__ dv,
                                              const int* __restrict__ start,
                                              const int* __restrict__ cnt,
                                              const float* __restrict__ E2,
                                              float* out, int N) {
    int wid = blockIdx.x * 4 + (threadIdx.x >> 6);
    if (wid >= N) return;
    int lane = threadIdx.x & 63;
    int hl = lane >> 5;
    int l  = lane & 31;
    int p = start[wid], c = cnt[wid];
    float a0 = 0.f, a1 = 0.f, a2 = 0.f, a3 = 0.f;
    int j = hl;
    for (; j + 2 < c; j += 4) {
        int2 s0 = slot[p + j];
        int2 s1 = slot[p + j + 2];
        float c0 = __int_as_float(s0.y), c1 = __int_as_float(s1.y);
        float4 v0 = *(const float4*)(E2 + (size_t)s0.x * F + l * 4);
        float4 v1 = *(const float4*)(E2 + (size_t)s1.x * F + l * 4);
        a0 += c0 * v0.x + c1 * v1.x;
        a1 += c0 * v0.y + c1 * v1.y;
        a2 += c0 * v0.z + c1 * v1.z;
        a3 += c0 * v0.w + c1 * v1.w;
    }
    if (j < c) {
        int2 s0 = slot[p + j];
        float c0 = __int_as_float(s0.y);
        float4 v0 = *(const float4*)(E2 + (size_t)s0.x * F + l * 4);
        a0 += c0 * v0.x; a1 += c0 * v0.y; a2 += c0 * v0.z; a3 += c0 * v0.w;
    }
    a0 += __shfl_xor(a0, 32);
    a1 += __shfl_xor(a1, 32);
    a2 += __shfl_xor(a2, 32);
    a3 += __shfl_xor(a3, 32);
    if (hl == 0) {
        float dvn = dv[wid];
        float4 xv = *(const float4*)(xm + (size_t)wid * F + l * 4);
        *(float4*)(out + (size_t)wid * F + l * 4) =
            make_float4(a0 * dvn + xv.x, a1 * dvn + xv.y,
                        a2 * dvn + xv.z, a3 * dvn + xv.w);
    }
}

extern "C" void kernel_launch(void* const* d_in, const int* in_sizes, int n_in,
                              void* d_out, int out_size, void* d_ws, size_t ws_size,
                              hipStream_t stream) {
    const float* x      = (const float*)d_in[0];
    const float* w      = (const float*)d_in[1];
    const float* bias   = (const float*)d_in[2];
    const int*   ni     = (const int*)d_in[3];
    const int*   ei     = (const int*)d_in[4];
    const float* hv     = (const float*)d_in[5];
    const float* dv     = (const float*)d_in[6];
    const float* de     = (const float*)d_in[7];
    float* out = (float*)d_out;

    const int N   = in_sizes[0] / F;   // 100000
    const int NNZ = in_sizes[3];       // 1600000
    const int M   = in_sizes[7];       // 20000 (== M_E)

    // workspace layout (4B units) — ~73 MB total
    int* wsp        = (int*)d_ws;
    int* edge_cnt   = wsp;                        // 20000
    int* node_cnt   = edge_cnt + M;               // 100000
    int* edge_start = node_cnt + N;               // 20000
    int* node_start = edge_start + M;             // 100000
    int* partE      = node_start + N;             // 256
    int* partN      = partE + 256;                // 256
    int* partE2     = partN + 256;                // NBE*20000    = 5.12M
    int* partN2     = partE2 + (size_t)NBE * M_E; // R_N*NBN*25000= 6.4M
    int2* eslot     = (int2*)(partN2 + (size_t)R_N * NBN * RB_N); // NNZ int2
    int2* nslot     = eslot + NNZ;                // NNZ int2
    // E2 aliases partN2 (consumed by kC_n before k_edge writes E2)
    float* E2       = (float*)partN2;             // M*F floats (10.24MB <= 25.6MB)

    const int gScanE = (M + 1023) / 1024;    // 20
    const int gScanN = (N + 1023) / 1024;    // 98

    k_gemm<<<(N + 127) / 128, 256, 0, stream>>>(x, w, bias, out, N);

    kA_e<<<NBE, 512, 0, stream>>>(ei, partE2, NNZ);
    kA_n<<<NBN * R_N, 512, 0, stream>>>(ni, partN2, NNZ);

    kB<<<(M + 255) / 256, 256, 0, stream>>>(partE2, edge_cnt, M, NBE);
    for (int r = 0; r < R_N; ++r)
        kB<<<(RB_N + 255) / 256, 256, 0, stream>>>(partN2 + (size_t)r * NBN * RB_N,
                                                   node_cnt + (size_t)r * RB_N, RB_N, NBN);

    k_scan1<<<gScanE, 256, 0, stream>>>(edge_cnt, edge_start, partE, M);
    k_scan1<<<gScanN, 256, 0, stream>>>(node_cnt, node_start, partN, N);
    k_scan2<<<1, 256, 0, stream>>>(partE, gScanE);
    k_scan2<<<1, 256, 0, stream>>>(partN, gScanN);
    k_scan3<<<(M + 255) / 256, 256, 0, stream>>>(edge_start, partE, M);
    k_scan3<<<(N + 255) / 256, 256, 0, stream>>>(node_start, partN, N);

    kC_e<<<NBE, 512, 0, stream>>>(ei, ni, hv, dv, edge_start, partE2, eslot, NNZ);
    kC_n<<<NBN * R_N, 512, 0, stream>>>(ei, ni, hv, node_start, partN2, nslot, NNZ);

    k_edge<<<(M + 3) / 4, 256, 0, stream>>>(out, eslot, de, edge_start, edge_cnt, E2, M);
    k_node<<<(N + 3) / 4, 256, 0, stream>>>(out, nslot, dv, node_start, node_cnt, E2, out, N);
}

// Round 13
// 523.837 us; speedup vs baseline: 1.7605x; 1.1241x over previous
//
#include <hip/hip_runtime.h>

// HGNN+ conv: y = dv*(H * de*(H^T * (dv*(XW+b)))) + (XW+b)
// ZERO global atomics. r11: k_edge gather = top cost (113us, FETCH 378MB,
// 3.5TB/s L2-miss BW). This round: bf16 gather tables (xmb 256B rows, E2b
// 5.12MB L2-resident), edge sort NBE 256->128 (partials 98.7% zero), order
// sorts->GEMM->gathers so xmb/E2b alias dead sort buffers.

#define F 128
#define NBE 128        // edge-side chunks (chunk = 12500)
#define NBN 64         // node-side chunks (chunk = 25000)
#define M_E 20000      // edge bins (80KB LDS)
#define RB_N 25000     // node bins per range (100KB LDS)
#define R_N 4          // node ranges

__device__ __forceinline__ unsigned short f2bf(float f) {
    unsigned u = __float_as_uint(f);
    unsigned r = (u + 0x7FFF + ((u >> 16) & 1)) >> 16;   // RNE
    return (unsigned short)r;
}
__device__ __forceinline__ float bf2f(unsigned short h) {
    return __uint_as_float((unsigned)h << 16);
}

// ---- Pass A: per-block LDS histogram -> partials -------------------------
__global__ __launch_bounds__(512) void kA_e(const int* __restrict__ ei,
                                            int* __restrict__ part2, int nnz) {
    __shared__ int sh[M_E];
    int b = blockIdx.x, t = threadIdx.x;
    for (int k = t; k < M_E; k += 512) sh[k] = 0;
    __syncthreads();
    int ch = (nnz + NBE - 1) / NBE;
    int i0 = b * ch, i1 = i0 + ch < nnz ? i0 + ch : nnz;
    for (int i = i0 + t; i < i1; i += 512) atomicAdd(&sh[ei[i]], 1);
    __syncthreads();
    for (int k = t; k < M_E; k += 512) part2[(size_t)b * M_E + k] = sh[k];
}

// block (b,r): b = blockIdx.x>>2 (chunk), r = blockIdx.x&3 (range)
__global__ __launch_bounds__(512) void kA_n(const int* __restrict__ ni,
                                            int* __restrict__ partN2, int nnz) {
    __shared__ int sh[RB_N];
    int b = blockIdx.x >> 2, r = blockIdx.x & 3, t = threadIdx.x;
    for (int k = t; k < RB_N; k += 512) sh[k] = 0;
    __syncthreads();
    int ch = (nnz + NBN - 1) / NBN;
    int i0 = b * ch, i1 = i0 + ch < nnz ? i0 + ch : nnz;
    int lo = r * RB_N;
    for (int i = i0 + t; i < i1; i += 512) {
        int lb = ni[i] - lo;
        if ((unsigned)lb < (unsigned)RB_N) atomicAdd(&sh[lb], 1);
    }
    __syncthreads();
    for (int k = t; k < RB_N; k += 512)
        partN2[((size_t)(r * NBN + b)) * RB_N + k] = sh[k];
}

// ---- Pass B: within-bin exclusive prefix over blocks + totals ------------
__global__ void kB(int* __restrict__ part2, int* __restrict__ cnt, int bins, int nb) {
    int bin = blockIdx.x * blockDim.x + threadIdx.x;
    if (bin >= bins) return;
    int run = 0;
#pragma unroll 8
    for (int b = 0; b < nb; ++b) {
        size_t idx = (size_t)b * bins + bin;
        int v = part2[idx];
        part2[idx] = run;
        run += v;
    }
    cnt[bin] = run;
}

// ---- hierarchical exclusive scan (cnt -> start) --------------------------
__global__ void k_scan1(const int* __restrict__ cnt, int* __restrict__ excl,
                        int* __restrict__ part, int n) {
    __shared__ int s[256];
    int t = threadIdx.x;
    int base = blockIdx.x * 1024 + t * 4;
    int v0 = (base + 0 < n) ? cnt[base + 0] : 0;
    int v1 = (base + 1 < n) ? cnt[base + 1] : 0;
    int v2 = (base + 2 < n) ? cnt[base + 2] : 0;
    int v3 = (base + 3 < n) ? cnt[base + 3] : 0;
    s[t] = v0 + v1 + v2 + v3;
    __syncthreads();
    for (int off = 1; off < 256; off <<= 1) {
        int add = (t >= off) ? s[t - off] : 0;
        __syncthreads();
        s[t] += add;
        __syncthreads();
    }
    int r = (t > 0) ? s[t - 1] : 0;
    if (base + 0 < n) excl[base + 0] = r; r += v0;
    if (base + 1 < n) excl[base + 1] = r; r += v1;
    if (base + 2 < n) excl[base + 2] = r; r += v2;
    if (base + 3 < n) excl[base + 3] = r;
    if (t == 255) part[blockIdx.x] = s[255];
}

__global__ void k_scan2(int* __restrict__ part, int n) {
    __shared__ int s[256];
    int t = threadIdx.x;
    s[t] = (t < n) ? part[t] : 0;
    __syncthreads();
    for (int off = 1; off < 256; off <<= 1) {
        int add = (t >= off) ? s[t - off] : 0;
        __syncthreads();
        s[t] += add;
        __syncthreads();
    }
    if (t < n) part[t] = (t > 0) ? s[t - 1] : 0;
}

__global__ void k_scan3(int* __restrict__ start, const int* __restrict__ part, int n) {
    int i = blockIdx.x * blockDim.x + threadIdx.x;
    if (i < n) start[i] += part[i >> 10];
}

// ---- Pass C: placement via LDS cursors (no global atomics) ---------------
__global__ __launch_bounds__(512) void kC_e(const int* __restrict__ ei, const int* __restrict__ ni,
                                            const float* __restrict__ hv, const float* __restrict__ dv,
                                            const int* __restrict__ start, const int* __restrict__ part2,
                                            int2* __restrict__ eslot, int nnz) {
    __shared__ int sh[M_E];
    int b = blockIdx.x, t = threadIdx.x;
    for (int k = t; k < M_E; k += 512)
        sh[k] = start[k] + part2[(size_t)b * M_E + k];
    __syncthreads();
    int ch = (nnz + NBE - 1) / NBE;
    int i0 = b * ch, i1 = i0 + ch < nnz ? i0 + ch : nnz;
    for (int i = i0 + t; i < i1; i += 512) {
        int e = ei[i], nd = ni[i];
        float v = hv[i] * dv[nd];
        int p = atomicAdd(&sh[e], 1);
        eslot[p] = make_int2(nd, __float_as_int(v));
    }
}

__global__ __launch_bounds__(512) void kC_n(const int* __restrict__ ei, const int* __restrict__ ni,
                                            const float* __restrict__ hv,
                                            const int* __restrict__ start, const int* __restrict__ partN2,
                                            int2* __restrict__ nslot, int nnz) {
    __shared__ int sh[RB_N];
    int b = blockIdx.x >> 2, r = blockIdx.x & 3, t = threadIdx.x;
    int lo = r * RB_N;
    for (int k = t; k < RB_N; k += 512)
        sh[k] = start[lo + k] + partN2[((size_t)(r * NBN + b)) * RB_N + k];
    __syncthreads();
    int ch = (nnz + NBN - 1) / NBN;
    int i0 = b * ch, i1 = i0 + ch < nnz ? i0 + ch : nnz;
    for (int i = i0 + t; i < i1; i += 512) {
        int lb = ni[i] - lo;
        if ((unsigned)lb < (unsigned)RB_N) {
            int e = ei[i];
            float h = hv[i];
            int p = atomicAdd(&sh[lb], 1);
            nslot[p] = make_int2(e, __float_as_int(h));
        }
    }
}

__device__ __forceinline__ float f4_get(const float4& v, int k) {
    return k == 0 ? v.x : k == 1 ? v.y : k == 2 ? v.z : v.w;
}

// ---- GEMM: out = x@w + bias (fp32) ; xmb = bf16 copy for gather ----------
__global__ __launch_bounds__(256) void k_gemm(const float* __restrict__ x,
                                              const float* __restrict__ w,
                                              const float* __restrict__ bias,
                                              float* __restrict__ y,
                                              unsigned short* __restrict__ xmb, int N) {
    __shared__ float sw[32 * 128];
    __shared__ float sx[128 * 36];
    int t = threadIdx.x;
    int row0 = blockIdx.x * 128;
    int cg = (t & 15) * 8;
    int rg = (t >> 4) * 8;
    float acc[8][8];
#pragma unroll
    for (int a = 0; a < 8; a++)
#pragma unroll
        for (int b = 0; b < 8; b++) acc[a][b] = 0.f;

    const float4* x4 = (const float4*)x;
    const float4* w4 = (const float4*)w;

    for (int kc = 0; kc < 4; ++kc) {
        __syncthreads();
        for (int i = t; i < 1024; i += 256) {
            int k = i >> 5, c4 = i & 31;
            ((float4*)sw)[i] = w4[(kc * 32 + k) * 32 + c4];
        }
        for (int i = t; i < 1024; i += 256) {
            int r = i >> 3, c4 = i & 7;
            float4 vv = make_float4(0.f, 0.f, 0.f, 0.f);
            if (row0 + r < N) vv = x4[(size_t)(row0 + r) * 32 + kc * 8 + c4];
            *(float4*)&sx[r * 36 + c4 * 4] = vv;
        }
        __syncthreads();
#pragma unroll
        for (int k4 = 0; k4 < 8; ++k4) {
            float4 xa[8];
#pragma unroll
            for (int rr = 0; rr < 8; rr++)
                xa[rr] = *(const float4*)&sx[(rg + rr) * 36 + k4 * 4];
#pragma unroll
            for (int kk = 0; kk < 4; kk++) {
                float4 wa0 = *(const float4*)&sw[(k4 * 4 + kk) * 128 + cg];
                float4 wa1 = *(const float4*)&sw[(k4 * 4 + kk) * 128 + cg + 4];
#pragma unroll
                for (int rr = 0; rr < 8; rr++) {
                    float xv = f4_get(xa[rr], kk);
                    acc[rr][0] += xv * wa0.x; acc[rr][1] += xv * wa0.y;
                    acc[rr][2] += xv * wa0.z; acc[rr][3] += xv * wa0.w;
                    acc[rr][4] += xv * wa1.x; acc[rr][5] += xv * wa1.y;
                    acc[rr][6] += xv * wa1.z; acc[rr][7] += xv * wa1.w;
                }
            }
        }
    }

    float4 b0 = *(const float4*)&bias[cg];
    float4 b1 = *(const float4*)&bias[cg + 4];
#pragma unroll
    for (int rr = 0; rr < 8; rr++) {
        int r = row0 + rg + rr;
        if (r < N) {
            float o[8] = {acc[rr][0] + b0.x, acc[rr][1] + b0.y,
                          acc[rr][2] + b0.z, acc[rr][3] + b0.w,
                          acc[rr][4] + b1.x, acc[rr][5] + b1.y,
                          acc[rr][6] + b1.z, acc[rr][7] + b1.w};
            *(float4*)&y[(size_t)r * F + cg]     = make_float4(o[0], o[1], o[2], o[3]);
            *(float4*)&y[(size_t)r * F + cg + 4] = make_float4(o[4], o[5], o[6], o[7]);
            ushort4 h0 = {f2bf(o[0]), f2bf(o[1]), f2bf(o[2]), f2bf(o[3])};
            ushort4 h1 = {f2bf(o[4]), f2bf(o[5]), f2bf(o[6]), f2bf(o[7])};
            *(ushort4*)&xmb[(size_t)r * F + cg]     = h0;
            *(ushort4*)&xmb[(size_t)r * F + cg + 4] = h1;
        }
    }
}

// ---- gathers (bf16 tables) -----------------------------------------------
// wave per hyperedge: E2b[e][:] = bf16( de[e] * sum_s val(s)*xmb[idx(s)][:] )
__global__ __launch_bounds__(256) void k_edge(const unsigned short* __restrict__ xmb,
                                              const int2* __restrict__ slot,
                                              const float* __restrict__ de,
                                              const int* __restrict__ start,
                                              const int* __restrict__ cnt,
                                              unsigned short* __restrict__ E2b, int M) {
    int wid = blockIdx.x * 4 + (threadIdx.x >> 6);
    if (wid >= M) return;
    int lane = threadIdx.x & 63;
    int hl = lane >> 5;
    int l  = lane & 31;
    int p = start[wid], c = cnt[wid];
    float a0 = 0.f, a1 = 0.f, a2 = 0.f, a3 = 0.f;
    int j = hl;
    for (; j + 2 < c; j += 4) {
        int2 s0 = slot[p + j];
        int2 s1 = slot[p + j + 2];
        float c0 = __int_as_float(s0.y), c1 = __int_as_float(s1.y);
        ushort4 v0 = *(const ushort4*)(xmb + (size_t)s0.x * F + l * 4);
        ushort4 v1 = *(const ushort4*)(xmb + (size_t)s1.x * F + l * 4);
        a0 += c0 * bf2f(v0.x) + c1 * bf2f(v1.x);
        a1 += c0 * bf2f(v0.y) + c1 * bf2f(v1.y);
        a2 += c0 * bf2f(v0.z) + c1 * bf2f(v1.z);
        a3 += c0 * bf2f(v0.w) + c1 * bf2f(v1.w);
    }
    if (j < c) {
        int2 s0 = slot[p + j];
        float c0 = __int_as_float(s0.y);
        ushort4 v0 = *(const ushort4*)(xmb + (size_t)s0.x * F + l * 4);
        a0 += c0 * bf2f(v0.x); a1 += c0 * bf2f(v0.y);
        a2 += c0 * bf2f(v0.z); a3 += c0 * bf2f(v0.w);
    }
    a0 += __shfl_xor(a0, 32);
    a1 += __shfl_xor(a1, 32);
    a2 += __shfl_xor(a2, 32);
    a3 += __shfl_xor(a3, 32);
    if (hl == 0) {
        float s = de[wid];
        ushort4 o = {f2bf(a0 * s), f2bf(a1 * s), f2bf(a2 * s), f2bf(a3 * s)};
        *(ushort4*)(E2b + (size_t)wid * F + l * 4) = o;
    }
}

// wave per node: out[n][:] = dv[n] * sum_s val(s)*E2b[idx(s)][:] + out[n][:]
__global__ __launch_bounds__(256) void k_node(const unsigned short* __restrict__ E2b,
                                              const int2* __restrict__ slot,
                                              const float* __restrict__ dv,
                                              const int* __restrict__ start,
                                              const int* __restrict__ cnt,
                                              float* out, int N) {
    int wid = blockIdx.x * 4 + (threadIdx.x >> 6);
    if (wid >= N) return;
    int lane = threadIdx.x & 63;
    int hl = lane >> 5;
    int l  = lane & 31;
    int p = start[wid], c = cnt[wid];
    float a0 = 0.f, a1 = 0.f, a2 = 0.f, a3 = 0.f;
    int j = hl;
    for (; j + 2 < c; j += 4) {
        int2 s0 = slot[p + j];
        int2 s1 = slot[p + j + 2];
        float c0 = __int_as_float(s0.y), c1 = __int_as_float(s1.y);
        ushort4 v0 = *(const ushort4*)(E2b + (size_t)s0.x * F + l * 4);
        ushort4 v1 = *(const ushort4*)(E2b + (size_t)s1.x * F + l * 4);
        a0 += c0 * bf2f(v0.x) + c1 * bf2f(v1.x);
        a1 += c0 * bf2f(v0.y) + c1 * bf2f(v1.y);
        a2 += c0 * bf2f(v0.z) + c1 * bf2f(v1.z);
        a3 += c0 * bf2f(v0.w) + c1 * bf2f(v1.w);
    }
    if (j < c) {
        int2 s0 = slot[p + j];
        float c0 = __int_as_float(s0.y);
        ushort4 v0 = *(const ushort4*)(E2b + (size_t)s0.x * F + l * 4);
        a0 += c0 * bf2f(v0.x); a1 += c0 * bf2f(v0.y);
        a2 += c0 * bf2f(v0.z); a3 += c0 * bf2f(v0.w);
    }
    a0 += __shfl_xor(a0, 32);
    a1 += __shfl_xor(a1, 32);
    a2 += __shfl_xor(a2, 32);
    a3 += __shfl_xor(a3, 32);
    if (hl == 0) {
        float dvn = dv[wid];
        float4 xv = *(const float4*)(out + (size_t)wid * F + l * 4);
        *(float4*)(out + (size_t)wid * F + l * 4) =
            make_float4(a0 * dvn + xv.x, a1 * dvn + xv.y,
                        a2 * dvn + xv.z, a3 * dvn + xv.w);
    }
}

extern "C" void kernel_launch(void* const* d_in, const int* in_sizes, int n_in,
                              void* d_out, int out_size, void* d_ws, size_t ws_size,
                              hipStream_t stream) {
    const float* x      = (const float*)d_in[0];
    const float* w      = (const float*)d_in[1];
    const float* bias   = (const float*)d_in[2];
    const int*   ni     = (const int*)d_in[3];
    const int*   ei     = (const int*)d_in[4];
    const float* hv     = (const float*)d_in[5];
    const float* dv     = (const float*)d_in[6];
    const float* de     = (const float*)d_in[7];
    float* out = (float*)d_out;

    const int N   = in_sizes[0] / F;   // 100000
    const int NNZ = in_sizes[3];       // 1600000
    const int M   = in_sizes[7];       // 20000 (== M_E)

    // workspace layout (4B units) — ~62.4 MB total
    int* wsp        = (int*)d_ws;
    int* edge_cnt   = wsp;                        // 20000
    int* node_cnt   = edge_cnt + M;               // 100000
    int* edge_start = node_cnt + N;               // 20000
    int* node_start = edge_start + M;             // 100000
    int* partE      = node_start + N;             // 256
    int* partN      = partE + 256;                // 256
    int* partE2     = partN + 256;                // NBE*20000    = 2.56M ints
    int* partN2     = partE2 + (size_t)NBE * M_E; // R_N*NBN*25000= 6.4M ints
    int2* eslot     = (int2*)(partN2 + (size_t)R_N * NBN * RB_N); // NNZ int2
    int2* nslot     = eslot + NNZ;                // NNZ int2
    // aliases (sorts run first; these regions are dead by GEMM/gather time):
    unsigned short* xmb = (unsigned short*)partN2; // N*128 ushort = 25.6MB == partN2 size
    unsigned short* E2b = (unsigned short*)partE2; // M*128 ushort = 5.12MB <= 10.24MB

    const int gScanE = (M + 1023) / 1024;    // 20
    const int gScanN = (N + 1023) / 1024;    // 98

    // ---- sorts first (their buffers die before GEMM/gathers) ----
    kA_e<<<NBE, 512, 0, stream>>>(ei, partE2, NNZ);
    kA_n<<<NBN * R_N, 512, 0, stream>>>(ni, partN2, NNZ);

    kB<<<(M + 255) / 256, 256, 0, stream>>>(partE2, edge_cnt, M, NBE);
    for (int r = 0; r < R_N; ++r)
        kB<<<(RB_N + 255) / 256, 256, 0, stream>>>(partN2 + (size_t)r * NBN * RB_N,
                                                   node_cnt + (size_t)r * RB_N, RB_N, NBN);

    k_scan1<<<gScanE, 256, 0, stream>>>(edge_cnt, edge_start, partE, M);
    k_scan1<<<gScanN, 256, 0, stream>>>(node_cnt, node_start, partN, N);
    k_scan2<<<1, 256, 0, stream>>>(partE, gScanE);
    k_scan2<<<1, 256, 0, stream>>>(partN, gScanN);
    k_scan3<<<(M + 255) / 256, 256, 0, stream>>>(edge_start, partE, M);
    k_scan3<<<(N + 255) / 256, 256, 0, stream>>>(node_start, partN, N);

    kC_e<<<NBE, 512, 0, stream>>>(ei, ni, hv, dv, edge_start, partE2, eslot, NNZ);
    kC_n<<<NBN * R_N, 512, 0, stream>>>(ei, ni, hv, node_start, partN2, nslot, NNZ);

    // ---- dense map (writes fp32 out + bf16 xmb into dead partN2) ----
    k_gemm<<<(N + 127) / 128, 256, 0, stream>>>(x, w, bias, out, xmb, N);

    // ---- gathers (bf16 tables) ----
    k_edge<<<(M + 3) / 4, 256, 0, stream>>>(xmb, eslot, de, edge_start, edge_cnt, E2b, M);
    k_node<<<(N + 3) / 4, 256, 0, stream>>>(E2b, nslot, dv, node_start, node_cnt, out, N);
}

// Round 14
// 515.441 us; speedup vs baseline: 1.7892x; 1.0163x over previous
//
#include <hip/hip_runtime.h>

// HGNN+ conv: y = dv*(H * de*(H^T * (dv*(XW+b)))) + (XW+b)
// ZERO global atomics. r13 counters: k_gemm 80us = top cost, 3.2M LDS bank
// conflicts, VALUBusy 31%, fp32-vector-bound. This round: GEMM -> bf16 MFMA
// (mfma_f32_16x16x32_bf16, m92-verified fragment pattern), zero LDS, fused
// bias + fp32 out + bf16 xmb epilogue. W pre-transposed to bf16 by k_wt.

#define F 128
#define NBE 128        // edge-side chunks (chunk = 12500)
#define NBN 64         // node-side chunks (chunk = 25000)
#define M_E 20000      // edge bins (80KB LDS)
#define RB_N 25000     // node bins per range (100KB LDS)
#define R_N 4          // node ranges

typedef __attribute__((ext_vector_type(8))) short bf16x8;
typedef __attribute__((ext_vector_type(4))) float f32x4;

__device__ __forceinline__ unsigned short f2bf(float f) {
    unsigned u = __float_as_uint(f);
    unsigned r = (u + 0x7FFF + ((u >> 16) & 1)) >> 16;   // RNE
    return (unsigned short)r;
}
__device__ __forceinline__ float bf2f(unsigned short h) {
    return __uint_as_float((unsigned)h << 16);
}

// ---- Pass A: per-block LDS histogram -> partials -------------------------
__global__ __launch_bounds__(512) void kA_e(const int* __restrict__ ei,
                                            int* __restrict__ part2, int nnz) {
    __shared__ int sh[M_E];
    int b = blockIdx.x, t = threadIdx.x;
    for (int k = t; k < M_E; k += 512) sh[k] = 0;
    __syncthreads();
    int ch = (nnz + NBE - 1) / NBE;
    int i0 = b * ch, i1 = i0 + ch < nnz ? i0 + ch : nnz;
    for (int i = i0 + t; i < i1; i += 512) atomicAdd(&sh[ei[i]], 1);
    __syncthreads();
    for (int k = t; k < M_E; k += 512) part2[(size_t)b * M_E + k] = sh[k];
}

// block (b,r): b = blockIdx.x>>2 (chunk), r = blockIdx.x&3 (range)
__global__ __launch_bounds__(512) void kA_n(const int* __restrict__ ni,
                                            int* __restrict__ partN2, int nnz) {
    __shared__ int sh[RB_N];
    int b = blockIdx.x >> 2, r = blockIdx.x & 3, t = threadIdx.x;
    for (int k = t; k < RB_N; k += 512) sh[k] = 0;
    __syncthreads();
    int ch = (nnz + NBN - 1) / NBN;
    int i0 = b * ch, i1 = i0 + ch < nnz ? i0 + ch : nnz;
    int lo = r * RB_N;
    for (int i = i0 + t; i < i1; i += 512) {
        int lb = ni[i] - lo;
        if ((unsigned)lb < (unsigned)RB_N) atomicAdd(&sh[lb], 1);
    }
    __syncthreads();
    for (int k = t; k < RB_N; k += 512)
        partN2[((size_t)(r * NBN + b)) * RB_N + k] = sh[k];
}

// ---- Pass B: within-bin exclusive prefix over blocks + totals ------------
__global__ void kB(int* __restrict__ part2, int* __restrict__ cnt, int bins, int nb) {
    int bin = blockIdx.x * blockDim.x + threadIdx.x;
    if (bin >= bins) return;
    int run = 0;
#pragma unroll 8
    for (int b = 0; b < nb; ++b) {
        size_t idx = (size_t)b * bins + bin;
        int v = part2[idx];
        part2[idx] = run;
        run += v;
    }
    cnt[bin] = run;
}

// ---- hierarchical exclusive scan (cnt -> start) --------------------------
__global__ void k_scan1(const int* __restrict__ cnt, int* __restrict__ excl,
                        int* __restrict__ part, int n) {
    __shared__ int s[256];
    int t = threadIdx.x;
    int base = blockIdx.x * 1024 + t * 4;
    int v0 = (base + 0 < n) ? cnt[base + 0] : 0;
    int v1 = (base + 1 < n) ? cnt[base + 1] : 0;
    int v2 = (base + 2 < n) ? cnt[base + 2] : 0;
    int v3 = (base + 3 < n) ? cnt[base + 3] : 0;
    s[t] = v0 + v1 + v2 + v3;
    __syncthreads();
    for (int off = 1; off < 256; off <<= 1) {
        int add = (t >= off) ? s[t - off] : 0;
        __syncthreads();
        s[t] += add;
        __syncthreads();
    }
    int r = (t > 0) ? s[t - 1] : 0;
    if (base + 0 < n) excl[base + 0] = r; r += v0;
    if (base + 1 < n) excl[base + 1] = r; r += v1;
    if (base + 2 < n) excl[base + 2] = r; r += v2;
    if (base + 3 < n) excl[base + 3] = r;
    if (t == 255) part[blockIdx.x] = s[255];
}

__global__ void k_scan2(int* __restrict__ part, int n) {
    __shared__ int s[256];
    int t = threadIdx.x;
    s[t] = (t < n) ? part[t] : 0;
    __syncthreads();
    for (int off = 1; off < 256; off <<= 1) {
        int add = (t >= off) ? s[t - off] : 0;
        __syncthreads();
        s[t] += add;
        __syncthreads();
    }
    if (t < n) part[t] = (t > 0) ? s[t - 1] : 0;
}

__global__ void k_scan3(int* __restrict__ start, const int* __restrict__ part, int n) {
    int i = blockIdx.x * blockDim.x + threadIdx.x;
    if (i < n) start[i] += part[i >> 10];
}

// ---- Pass C: placement via LDS cursors (no global atomics) ---------------
__global__ __launch_bounds__(512) void kC_e(const int* __restrict__ ei, const int* __restrict__ ni,
                                            const float* __restrict__ hv, const float* __restrict__ dv,
                                            const int* __restrict__ start, const int* __restrict__ part2,
                                            int2* __restrict__ eslot, int nnz) {
    __shared__ int sh[M_E];
    int b = blockIdx.x, t = threadIdx.x;
    for (int k = t; k < M_E; k += 512)
        sh[k] = start[k] + part2[(size_t)b * M_E + k];
    __syncthreads();
    int ch = (nnz + NBE - 1) / NBE;
    int i0 = b * ch, i1 = i0 + ch < nnz ? i0 + ch : nnz;
    for (int i = i0 + t; i < i1; i += 512) {
        int e = ei[i], nd = ni[i];
        float v = hv[i] * dv[nd];
        int p = atomicAdd(&sh[e], 1);
        eslot[p] = make_int2(nd, __float_as_int(v));
    }
}

__global__ __launch_bounds__(512) void kC_n(const int* __restrict__ ei, const int* __restrict__ ni,
                                            const float* __restrict__ hv,
                                            const int* __restrict__ start, const int* __restrict__ partN2,
                                            int2* __restrict__ nslot, int nnz) {
    __shared__ int sh[RB_N];
    int b = blockIdx.x >> 2, r = blockIdx.x & 3, t = threadIdx.x;
    int lo = r * RB_N;
    for (int k = t; k < RB_N; k += 512)
        sh[k] = start[lo + k] + partN2[((size_t)(r * NBN + b)) * RB_N + k];
    __syncthreads();
    int ch = (nnz + NBN - 1) / NBN;
    int i0 = b * ch, i1 = i0 + ch < nnz ? i0 + ch : nnz;
    for (int i = i0 + t; i < i1; i += 512) {
        int lb = ni[i] - lo;
        if ((unsigned)lb < (unsigned)RB_N) {
            int e = ei[i];
            float h = hv[i];
            int p = atomicAdd(&sh[lb], 1);
            nslot[p] = make_int2(e, __float_as_int(h));
        }
    }
}

// ---- W transpose+convert: wt[n][k] = bf16(w[k][n]) -----------------------
__global__ __launch_bounds__(256) void k_wt(const float* __restrict__ w,
                                            unsigned short* __restrict__ wt) {
    int i = blockIdx.x * 256 + threadIdx.x;      // 16384 elems
    int n = i >> 7, k = i & 127;
    wt[(size_t)n * F + k] = f2bf(w[(size_t)k * F + n]);
}

// ---- MFMA GEMM: out = x@w + bias (fp32) ; xmb = bf16 copy ----------------
// 4 waves/block, 128-row tile, no LDS. Wave wv owns rows [row0+wv*32, +32):
// 2 row-frags x 8 col-frags of 16x16, K=128 in 4 steps of 32.
// Fragment pattern (m92/m89-verified): A row-major M*K, lane reads
// x[row=lane&15][k0..k0+7], k0=(lane>>4)*8; B from wt (N*K), lane reads
// wt[col=lane&15][k0..k0+7]; C/D: col=lane&15, row=(lane>>4)*4+j.
__global__ __launch_bounds__(256) void k_gemm(const float* __restrict__ x,
                                              const unsigned short* __restrict__ wt,
                                              const float* __restrict__ bias,
                                              float* __restrict__ y,
                                              unsigned short* __restrict__ xmb, int N) {
    int t = threadIdx.x;
    int wv = t >> 6, lane = t & 63;
    int lrow = lane & 15, kg = lane >> 4;
    int row0 = blockIdx.x * 128 + wv * 32;

    f32x4 acc[2][8];
#pragma unroll
    for (int rf = 0; rf < 2; ++rf)
#pragma unroll
        for (int cf = 0; cf < 8; ++cf) acc[rf][cf] = (f32x4){0.f, 0.f, 0.f, 0.f};

#pragma unroll
    for (int ks = 0; ks < 4; ++ks) {
        bf16x8 a[2];
#pragma unroll
        for (int rf = 0; rf < 2; ++rf) {
            int r = row0 + rf * 16 + lrow;
            float4 q0 = make_float4(0.f, 0.f, 0.f, 0.f);
            float4 q1 = make_float4(0.f, 0.f, 0.f, 0.f);
            if (r < N) {
                const float* xp = x + (size_t)r * F + ks * 32 + kg * 8;
                q0 = *(const float4*)xp;
                q1 = *(const float4*)(xp + 4);
            }
            bf16x8 av;
            av[0] = (short)f2bf(q0.x); av[1] = (short)f2bf(q0.y);
            av[2] = (short)f2bf(q0.z); av[3] = (short)f2bf(q0.w);
            av[4] = (short)f2bf(q1.x); av[5] = (short)f2bf(q1.y);
            av[6] = (short)f2bf(q1.z); av[7] = (short)f2bf(q1.w);
            a[rf] = av;
        }
#pragma unroll
        for (int cf = 0; cf < 8; ++cf) {
            bf16x8 b = *(const bf16x8*)(wt + ((size_t)(cf * 16 + lrow)) * F + ks * 32 + kg * 8);
            acc[0][cf] = __builtin_amdgcn_mfma_f32_16x16x32_bf16(a[0], b, acc[0][cf], 0, 0, 0);
            acc[1][cf] = __builtin_amdgcn_mfma_f32_16x16x32_bf16(a[1], b, acc[1][cf], 0, 0, 0);
        }
    }

#pragma unroll
    for (int cf = 0; cf < 8; ++cf) {
        int c = cf * 16 + lrow;
        float bb = bias[c];
#pragma unroll
        for (int rf = 0; rf < 2; ++rf) {
#pragma unroll
            for (int j = 0; j < 4; ++j) {
                int r = row0 + rf * 16 + kg * 4 + j;
                if (r < N) {
                    float o = acc[rf][cf][j] + bb;
                    y[(size_t)r * F + c] = o;
                    xmb[(size_t)r * F + c] = f2bf(o);
                }
            }
        }
    }
}

// ---- gathers (bf16 tables) -----------------------------------------------
__global__ __launch_bounds__(256) void k_edge(const unsigned short* __restrict__ xmb,
                                              const int2* __restrict__ slot,
                                              const float* __restrict__ de,
                                              const int* __restrict__ start,
                                              const int* __restrict__ cnt,
                                              unsigned short* __restrict__ E2b, int M) {
    int wid = blockIdx.x * 4 + (threadIdx.x >> 6);
    if (wid >= M) return;
    int lane = threadIdx.x & 63;
    int hl = lane >> 5;
    int l  = lane & 31;
    int p = start[wid], c = cnt[wid];
    float a0 = 0.f, a1 = 0.f, a2 = 0.f, a3 = 0.f;
    int j = hl;
    for (; j + 2 < c; j += 4) {
        int2 s0 = slot[p + j];
        int2 s1 = slot[p + j + 2];
        float c0 = __int_as_float(s0.y), c1 = __int_as_float(s1.y);
        ushort4 v0 = *(const ushort4*)(xmb + (size_t)s0.x * F + l * 4);
        ushort4 v1 = *(const ushort4*)(xmb + (size_t)s1.x * F + l * 4);
        a0 += c0 * bf2f(v0.x) + c1 * bf2f(v1.x);
        a1 += c0 * bf2f(v0.y) + c1 * bf2f(v1.y);
        a2 += c0 * bf2f(v0.z) + c1 * bf2f(v1.z);
        a3 += c0 * bf2f(v0.w) + c1 * bf2f(v1.w);
    }
    if (j < c) {
        int2 s0 = slot[p + j];
        float c0 = __int_as_float(s0.y);
        ushort4 v0 = *(const ushort4*)(xmb + (size_t)s0.x * F + l * 4);
        a0 += c0 * bf2f(v0.x); a1 += c0 * bf2f(v0.y);
        a2 += c0 * bf2f(v0.z); a3 += c0 * bf2f(v0.w);
    }
    a0 += __shfl_xor(a0, 32);
    a1 += __shfl_xor(a1, 32);
    a2 += __shfl_xor(a2, 32);
    a3 += __shfl_xor(a3, 32);
    if (hl == 0) {
        float s = de[wid];
        ushort4 o = {f2bf(a0 * s), f2bf(a1 * s), f2bf(a2 * s), f2bf(a3 * s)};
        *(ushort4*)(E2b + (size_t)wid * F + l * 4) = o;
    }
}

__global__ __launch_bounds__(256) void k_node(const unsigned short* __restrict__ E2b,
                                              const int2* __restrict__ slot,
                                              const float* __restrict__ dv,
                                              const int* __restrict__ start,
                                              const int* __restrict__ cnt,
                                              float* out, int N) {
    int wid = blockIdx.x * 4 + (threadIdx.x >> 6);
    if (wid >= N) return;
    int lane = threadIdx.x & 63;
    int hl = lane >> 5;
    int l  = lane & 31;
    int p = start[wid], c = cnt[wid];
    float a0 = 0.f, a1 = 0.f, a2 = 0.f, a3 = 0.f;
    int j = hl;
    for (; j + 2 < c; j += 4) {
        int2 s0 = slot[p + j];
        int2 s1 = slot[p + j + 2];
        float c0 = __int_as_float(s0.y), c1 = __int_as_float(s1.y);
        ushort4 v0 = *(const ushort4*)(E2b + (size_t)s0.x * F + l * 4);
        ushort4 v1 = *(const ushort4*)(E2b + (size_t)s1.x * F + l * 4);
        a0 += c0 * bf2f(v0.x) + c1 * bf2f(v1.x);
        a1 += c0 * bf2f(v0.y) + c1 * bf2f(v1.y);
        a2 += c0 * bf2f(v0.z) + c1 * bf2f(v1.z);
        a3 += c0 * bf2f(v0.w) + c1 * bf2f(v1.w);
    }
    if (j < c) {
        int2 s0 = slot[p + j];
        float c0 = __int_as_float(s0.y);
        ushort4 v0 = *(const ushort4*)(E2b + (size_t)s0.x * F + l * 4);
        a0 += c0 * bf2f(v0.x); a1 += c0 * bf2f(v0.y);
        a2 += c0 * bf2f(v0.z); a3 += c0 * bf2f(v0.w);
    }
    a0 += __shfl_xor(a0, 32);
    a1 += __shfl_xor(a1, 32);
    a2 += __shfl_xor(a2, 32);
    a3 += __shfl_xor(a3, 32);
    if (hl == 0) {
        float dvn = dv[wid];
        float4 xv = *(const float4*)(out + (size_t)wid * F + l * 4);
        *(float4*)(out + (size_t)wid * F + l * 4) =
            make_float4(a0 * dvn + xv.x, a1 * dvn + xv.y,
                        a2 * dvn + xv.z, a3 * dvn + xv.w);
    }
}

extern "C" void kernel_launch(void* const* d_in, const int* in_sizes, int n_in,
                              void* d_out, int out_size, void* d_ws, size_t ws_size,
                              hipStream_t stream) {
    const float* x      = (const float*)d_in[0];
    const float* w      = (const float*)d_in[1];
    const float* bias   = (const float*)d_in[2];
    const int*   ni     = (const int*)d_in[3];
    const int*   ei     = (const int*)d_in[4];
    const float* hv     = (const float*)d_in[5];
    const float* dv     = (const float*)d_in[6];
    const float* de     = (const float*)d_in[7];
    float* out = (float*)d_out;

    const int N   = in_sizes[0] / F;   // 100000
    const int NNZ = in_sizes[3];       // 1600000
    const int M   = in_sizes[7];       // 20000 (== M_E)

    // workspace layout (4B units) — ~62.4 MB total
    int* wsp        = (int*)d_ws;
    int* edge_cnt   = wsp;                        // 20000
    int* node_cnt   = edge_cnt + M;               // 100000
    int* edge_start = node_cnt + N;               // 20000
    int* node_start = edge_start + M;             // 100000
    int* partE      = node_start + N;             // 256
    int* partN      = partE + 256;                // 256
    int* partE2     = partN + 256;                // NBE*20000    = 2.56M ints
    int* partN2     = partE2 + (size_t)NBE * M_E; // R_N*NBN*25000= 6.4M ints
    int2* eslot     = (int2*)(partN2 + (size_t)R_N * NBN * RB_N); // NNZ int2
    int2* nslot     = eslot + NNZ;                // NNZ int2
    unsigned short* wtb = (unsigned short*)(nslot + NNZ); // 16384 ushort (32KB)
    // aliases (sorts run first; these regions are dead by GEMM/gather time):
    unsigned short* xmb = (unsigned short*)partN2; // N*128 ushort = 25.6MB
    unsigned short* E2b = (unsigned short*)partE2; // M*128 ushort = 5.12MB

    const int gScanE = (M + 1023) / 1024;    // 20
    const int gScanN = (N + 1023) / 1024;    // 98

    // ---- W prep (independent) + sorts first ----
    k_wt<<<64, 256, 0, stream>>>(w, wtb);

    kA_e<<<NBE, 512, 0, stream>>>(ei, partE2, NNZ);
    kA_n<<<NBN * R_N, 512, 0, stream>>>(ni, partN2, NNZ);

    kB<<<(M + 255) / 256, 256, 0, stream>>>(partE2, edge_cnt, M, NBE);
    for (int r = 0; r < R_N; ++r)
        kB<<<(RB_N + 255) / 256, 256, 0, stream>>>(partN2 + (size_t)r * NBN * RB_N,
                                                   node_cnt + (size_t)r * RB_N, RB_N, NBN);

    k_scan1<<<gScanE, 256, 0, stream>>>(edge_cnt, edge_start, partE, M);
    k_scan1<<<gScanN, 256, 0, stream>>>(node_cnt, node_start, partN, N);
    k_scan2<<<1, 256, 0, stream>>>(partE, gScanE);
    k_scan2<<<1, 256, 0, stream>>>(partN, gScanN);
    k_scan3<<<(M + 255) / 256, 256, 0, stream>>>(edge_start, partE, M);
    k_scan3<<<(N + 255) / 256, 256, 0, stream>>>(node_start, partN, N);

    kC_e<<<NBE, 512, 0, stream>>>(ei, ni, hv, dv, edge_start, partE2, eslot, NNZ);
    kC_n<<<NBN * R_N, 512, 0, stream>>>(ei, ni, hv, node_start, partN2, nslot, NNZ);

    // ---- dense map: MFMA bf16 (fp32 out + bf16 xmb into dead partN2) ----
    k_gemm<<<(N + 127) / 128, 256, 0, stream>>>(x, wtb, bias, out, xmb, N);

    // ---- gathers (bf16 tables) ----
    k_edge<<<(M + 3) / 4, 256, 0, stream>>>(xmb, eslot, de, edge_start, edge_cnt, E2b, M);
    k_node<<<(N + 3) / 4, 256, 0, stream>>>(E2b, nslot, dv, node_start, node_cnt, out, N);
}